// Round 1
// baseline (8369.127 us; speedup 1.0000x reference)
//
#include <hip/hip_runtime.h>

#define NODES 100000
#define EDGES 100000
#define NNZV  1600000

// ---------------- degrees ----------------
__global__ void deg_kernel(const int* __restrict__ nidx, const int* __restrict__ eidx,
                           float* __restrict__ degv, float* __restrict__ dege, int nnz) {
  int j = blockIdx.x * blockDim.x + threadIdx.x;
  if (j < nnz) {
    unsafeAtomicAdd(&degv[nidx[j]], 1.0f);
    unsafeAtomicAdd(&dege[eidx[j]], 1.0f);
  }
}

__global__ void inv_kernel(float* __restrict__ d, int n) {
  int i = blockIdx.x * blockDim.x + threadIdx.x;
  if (i < n) { float v = d[i]; d[i] = (v > 0.f) ? (1.0f / v) : 0.f; }
}

// ---------------- GEMM: Y[M,N] = X[M,128] @ W[128,N] ----------------
template<int N>
__global__ __launch_bounds__(256) void gemm_kernel(const float* __restrict__ X,
                                                   const float* __restrict__ W,
                                                   float* __restrict__ Y, int M) {
  __shared__ float sW[128 * N];        // k-major; scalar reads are 2-way aliased (free)
  __shared__ float sX[4][8 * 128];     // per-wave 8-row staging
  const int tid = threadIdx.x, wave = tid >> 6, lane = tid & 63;
  for (int i = tid * 4; i < 128 * N; i += 1024)
    *(float4*)(sW + i) = *(const float4*)(W + i);
  __syncthreads();
  constexpr int CPL = N / 64;          // cols per lane: 2 (N=128) or 1 (N=64)
  for (int chunk = blockIdx.x * 32; chunk < M; chunk += gridDim.x * 32) {
    const int row0 = chunk + wave * 8;
    {
      const float4* src = (const float4*)(X + (size_t)row0 * 128);
      float4* dst = (float4*)sX[wave];
      #pragma unroll
      for (int i = 0; i < 4; i++) dst[lane + 64 * i] = src[lane + 64 * i];
      // same-wave LDS RAW: DS pipe is in-order per wave; compiler inserts lgkmcnt
    }
    float acc[8][CPL];
    #pragma unroll
    for (int r = 0; r < 8; r++)
      #pragma unroll
      for (int c = 0; c < CPL; c++) acc[r][c] = 0.f;
    const float* xw = sX[wave];
    #pragma unroll 2
    for (int k = 0; k < 128; k += 4) {
      float4 xr[8];
      #pragma unroll
      for (int r = 0; r < 8; r++) xr[r] = *(const float4*)(xw + r * 128 + k); // broadcast
      #pragma unroll
      for (int kk = 0; kk < 4; kk++) {
        #pragma unroll
        for (int c = 0; c < CPL; c++) {
          float w = sW[(k + kk) * N + lane + 64 * c];
          #pragma unroll
          for (int r = 0; r < 8; r++)
            acc[r][c] = fmaf(((const float*)&xr[r])[kk], w, acc[r][c]);
        }
      }
    }
    #pragma unroll
    for (int r = 0; r < 8; r++)
      #pragma unroll
      for (int c = 0; c < CPL; c++)
        Y[(size_t)(row0 + r) * N + lane + 64 * c] = acc[r][c];
  }
}

// ---------------- scatter: node -> edge (raw sum) ----------------
template<int F>
__global__ void scatter_n2e(const int* __restrict__ nidx, const int* __restrict__ eidx,
                            const float* __restrict__ src, float* __restrict__ dst, int nnz) {
  constexpr int G = F / 4;
  unsigned t = blockIdx.x * blockDim.x + threadIdx.x;
  int j = (int)(t / G);
  int f = (int)(t % G) * 4;
  if (j >= nnz) return;
  int v = nidx[j], e = eidx[j];
  float4 val = *(const float4*)(src + (size_t)v * F + f);
  float* d = dst + (size_t)e * F + f;
  unsafeAtomicAdd(d + 0, val.x);
  unsafeAtomicAdd(d + 1, val.y);
  unsafeAtomicAdd(d + 2, val.z);
  unsafeAtomicAdd(d + 3, val.w);
}

// ---------------- scatter: edge -> node (scaled by b_inv[e]) ----------------
template<int F>
__global__ void scatter_e2n(const int* __restrict__ nidx, const int* __restrict__ eidx,
                            const float* __restrict__ src, const float* __restrict__ scale,
                            float* __restrict__ dst, int nnz) {
  constexpr int G = F / 4;
  unsigned t = blockIdx.x * blockDim.x + threadIdx.x;
  int j = (int)(t / G);
  int f = (int)(t % G) * 4;
  if (j >= nnz) return;
  int v = nidx[j], e = eidx[j];
  float s = scale[e];
  float4 val = *(const float4*)(src + (size_t)e * F + f);
  float* d = dst + (size_t)v * F + f;
  unsafeAtomicAdd(d + 0, val.x * s);
  unsafeAtomicAdd(d + 1, val.y * s);
  unsafeAtomicAdd(d + 2, val.z * s);
  unsafeAtomicAdd(d + 3, val.w * s);
}

// ---------------- epilogue: y = y*dinv[v] + bias (+relu) ----------------
template<int F, bool RELU>
__global__ void epilogue_kernel(float* __restrict__ y, const float* __restrict__ dinv,
                                const float* __restrict__ bias, int n) {
  constexpr int G = F / 4;
  unsigned t = blockIdx.x * blockDim.x + threadIdx.x;
  if (t >= (unsigned)n * G) return;
  int v = (int)(t / G);
  int f = (int)(t % G) * 4;
  float s = dinv[v];
  float4 val = *(float4*)(y + (size_t)v * F + f);
  float4 b = *(const float4*)(bias + f);
  val.x = val.x * s + b.x;
  val.y = val.y * s + b.y;
  val.z = val.z * s + b.z;
  val.w = val.w * s + b.w;
  if (RELU) {
    val.x = fmaxf(val.x, 0.f);
    val.y = fmaxf(val.y, 0.f);
    val.z = fmaxf(val.z, 0.f);
    val.w = fmaxf(val.w, 0.f);
  }
  *(float4*)(y + (size_t)v * F + f) = val;
}

extern "C" void kernel_launch(void* const* d_in, const int* in_sizes, int n_in,
                              void* d_out, int out_size, void* d_ws, size_t ws_size,
                              hipStream_t stream) {
  const float* x  = (const float*)d_in[0];
  const int*   hi = (const int*)d_in[1];
  const float* W1 = (const float*)d_in[2];
  const float* b1 = (const float*)d_in[3];
  const float* W2 = (const float*)d_in[4];
  const float* b2 = (const float*)d_in[5];
  float* out = (float*)d_out;
  const int* nidx = hi;             // row 0: node indices
  const int* eidx = hi + NNZV;      // row 1: edge indices

  char* ws = (char*)d_ws;
  float* degv = (float*)ws;                               // 100000 f32 -> D^-1
  float* dege = (float*)(ws + 400000);                    // 100000 f32 -> B^-1
  float* bufA = (float*)(ws + 1048576);                   // 51.2 MB
  float* bufB = (float*)(ws + 1048576 + 51200000);        // 51.2 MB

  // degrees + inverses
  hipMemsetAsync(degv, 0, 800000, stream);
  deg_kernel<<<(NNZV + 255) / 256, 256, 0, stream>>>(nidx, eidx, degv, dege, NNZV);
  inv_kernel<<<(200000 + 255) / 256, 256, 0, stream>>>(degv, 200000);

  // ---- conv1 (F=128) ----
  gemm_kernel<128><<<512, 256, 0, stream>>>(x, W1, bufA, NODES);                 // h1 = x@W1
  hipMemsetAsync(bufB, 0, (size_t)EDGES * 128 * 4, stream);
  scatter_n2e<128><<<(NNZV * 32 + 255) / 256, 256, 0, stream>>>(nidx, eidx, bufA, bufB, NNZV);
  hipMemsetAsync(bufA, 0, (size_t)NODES * 128 * 4, stream);
  scatter_e2n<128><<<(NNZV * 32 + 255) / 256, 256, 0, stream>>>(nidx, eidx, bufB, dege, bufA, NNZV);
  epilogue_kernel<128, true><<<(NODES * 32 + 255) / 256, 256, 0, stream>>>(bufA, degv, b1, NODES);

  // ---- conv2 (F=64) ----
  gemm_kernel<64><<<768, 256, 0, stream>>>(bufA, W2, bufB, NODES);               // h2 = h@W2
  hipMemsetAsync(bufA, 0, (size_t)EDGES * 64 * 4, stream);
  scatter_n2e<64><<<(NNZV * 16 + 255) / 256, 256, 0, stream>>>(nidx, eidx, bufB, bufA, NNZV);
  hipMemsetAsync(out, 0, (size_t)NODES * 64 * 4, stream);
  scatter_e2n<64><<<(NNZV * 16 + 255) / 256, 256, 0, stream>>>(nidx, eidx, bufA, dege, out, NNZV);
  epilogue_kernel<64, false><<<(NODES * 16 + 255) / 256, 256, 0, stream>>>(out, degv, b2, NODES);
}

// Round 2
// 1028.082 us; speedup vs baseline: 8.1405x; 8.1405x over previous
//
#include <hip/hip_runtime.h>

#define NODES 100000
#define EDGES 100000
#define NNZV  1600000

// ================= CSR build =================
__global__ void hist_kernel(const int* __restrict__ nidx, const int* __restrict__ eidx,
                            int* __restrict__ cnt_v, int* __restrict__ cnt_e, int nnz) {
  int j = blockIdx.x * blockDim.x + threadIdx.x;
  if (j < nnz) {
    atomicAdd(&cnt_e[eidx[j]], 1);
    atomicAdd(&cnt_v[nidx[j]], 1);
  }
}

// one block per array: exclusive scan of counts -> off[0..n], rewrite counts as cursors
__global__ __launch_bounds__(1024) void scan_kernel(int* __restrict__ cur_e, int* __restrict__ off_e,
                                                    int* __restrict__ cur_v, int* __restrict__ off_v, int n) {
  int* cnt = blockIdx.x ? cur_v : cur_e;
  int* off = blockIdx.x ? off_v : off_e;
  __shared__ int ws[17];
  __shared__ int carry_s;
  const int tid = threadIdx.x, lane = tid & 63, wid = tid >> 6;
  if (tid == 0) carry_s = 0;
  __syncthreads();
  for (int base = 0; base < n; base += 1024) {
    int i = base + tid;
    int v = (i < n) ? cnt[i] : 0;
    int x = v;
    #pragma unroll
    for (int d = 1; d < 64; d <<= 1) { int t = __shfl_up(x, d); if (lane >= d) x += t; }
    if (lane == 63) ws[wid] = x;
    __syncthreads();
    if (tid == 0) { int a = 0; for (int k = 0; k < 16; k++) { int t = ws[k]; ws[k] = a; a += t; } ws[16] = a; }
    __syncthreads();
    int excl = carry_s + ws[wid] + x - v;
    if (i < n) { off[i] = excl; cnt[i] = excl; }   // cnt becomes fill cursor
    __syncthreads();
    if (tid == 0) carry_s += ws[16];
    __syncthreads();
  }
  if (tid == 0) off[n] = carry_s;
}

__global__ void fill_kernel(const int* __restrict__ nidx, const int* __restrict__ eidx,
                            int* __restrict__ cur_v, int* __restrict__ cur_e,
                            int* __restrict__ col_v, int* __restrict__ col_e, int nnz) {
  int j = blockIdx.x * blockDim.x + threadIdx.x;
  if (j < nnz) {
    int v = nidx[j], e = eidx[j];
    int p = atomicAdd(&cur_e[e], 1); col_e[p] = v;   // edge -> member nodes
    int q = atomicAdd(&cur_v[v], 1); col_v[q] = e;   // node -> member edges
  }
}

// ================= GEMM: Y[M,N] = X[M,128] @ W[128,N] =================
template<int N>
__global__ __launch_bounds__(256) void gemm_kernel(const float* __restrict__ X,
                                                   const float* __restrict__ W,
                                                   float* __restrict__ Y, int M) {
  __shared__ float sW[128 * N];
  __shared__ float sX[4][8 * 128];
  const int tid = threadIdx.x, wave = tid >> 6, lane = tid & 63;
  for (int i = tid * 4; i < 128 * N; i += 1024)
    *(float4*)(sW + i) = *(const float4*)(W + i);
  __syncthreads();
  constexpr int CPL = N / 64;
  for (int chunk = blockIdx.x * 32; chunk < M; chunk += gridDim.x * 32) {
    const int row0 = chunk + wave * 8;
    {
      const float4* src = (const float4*)(X + (size_t)row0 * 128);
      float4* dst = (float4*)sX[wave];
      #pragma unroll
      for (int i = 0; i < 4; i++) dst[lane + 64 * i] = src[lane + 64 * i];
    }
    float acc[8][CPL];
    #pragma unroll
    for (int r = 0; r < 8; r++)
      #pragma unroll
      for (int c = 0; c < CPL; c++) acc[r][c] = 0.f;
    const float* xw = sX[wave];
    #pragma unroll 2
    for (int k = 0; k < 128; k += 4) {
      float4 xr[8];
      #pragma unroll
      for (int r = 0; r < 8; r++) xr[r] = *(const float4*)(xw + r * 128 + k);
      #pragma unroll
      for (int kk = 0; kk < 4; kk++) {
        #pragma unroll
        for (int c = 0; c < CPL; c++) {
          float w = sW[(k + kk) * N + lane + 64 * c];
          #pragma unroll
          for (int r = 0; r < 8; r++)
            acc[r][c] = fmaf(((const float*)&xr[r])[kk], w, acc[r][c]);
        }
      }
    }
    #pragma unroll
    for (int r = 0; r < 8; r++)
      #pragma unroll
      for (int c = 0; c < CPL; c++)
        Y[(size_t)(row0 + r) * N + lane + 64 * c] = acc[r][c];
  }
}

// ========== gather node->edge: dst[e] = (1/deg_e) * sum_{v in e} src[v] ==========
template<int F>
__global__ __launch_bounds__(256) void gather_n2e(const int* __restrict__ off, const int* __restrict__ col,
                                                  const float* __restrict__ src, float* __restrict__ dst,
                                                  int nrows) {
  constexpr int VPT = F / 64;                 // floats per lane
  const int row = blockIdx.x * 4 + (threadIdx.x >> 6);
  if (row >= nrows) return;
  const int lane = threadIdx.x & 63;
  const int s0 = off[row], s1 = off[row + 1];
  float acc0[VPT] = {}, acc1[VPT] = {};
  int k = s0;
  for (; k + 1 < s1; k += 2) {
    int c0 = col[k], c1 = col[k + 1];
    const float* p0 = src + (size_t)c0 * F + lane * VPT;
    const float* p1 = src + (size_t)c1 * F + lane * VPT;
    if constexpr (VPT == 2) {
      float2 a = *(const float2*)p0, b = *(const float2*)p1;
      acc0[0] += a.x; acc0[1] += a.y; acc1[0] += b.x; acc1[1] += b.y;
    } else { acc0[0] += *p0; acc1[0] += *p1; }
  }
  if (k < s1) {
    const float* p0 = src + (size_t)col[k] * F + lane * VPT;
    if constexpr (VPT == 2) { float2 a = *(const float2*)p0; acc0[0] += a.x; acc0[1] += a.y; }
    else acc0[0] += *p0;
  }
  const float sc = (s1 > s0) ? 1.0f / (float)(s1 - s0) : 0.f;
  float* d = dst + (size_t)row * F + lane * VPT;
  if constexpr (VPT == 2) { *(float2*)d = make_float2((acc0[0] + acc1[0]) * sc, (acc0[1] + acc1[1]) * sc); }
  else d[0] = (acc0[0] + acc1[0]) * sc;
}

// ====== gather edge->node + bias (+relu): out[v] = relu((1/deg_v)*sum src[e] + b) ======
template<int F, bool RELU>
__global__ __launch_bounds__(256) void gather_e2n(const int* __restrict__ off, const int* __restrict__ col,
                                                  const float* __restrict__ src, const float* __restrict__ bias,
                                                  float* __restrict__ dst, int nrows) {
  constexpr int VPT = F / 64;
  const int row = blockIdx.x * 4 + (threadIdx.x >> 6);
  if (row >= nrows) return;
  const int lane = threadIdx.x & 63;
  const int s0 = off[row], s1 = off[row + 1];
  float acc0[VPT] = {}, acc1[VPT] = {};
  int k = s0;
  for (; k + 1 < s1; k += 2) {
    int c0 = col[k], c1 = col[k + 1];
    const float* p0 = src + (size_t)c0 * F + lane * VPT;
    const float* p1 = src + (size_t)c1 * F + lane * VPT;
    if constexpr (VPT == 2) {
      float2 a = *(const float2*)p0, b = *(const float2*)p1;
      acc0[0] += a.x; acc0[1] += a.y; acc1[0] += b.x; acc1[1] += b.y;
    } else { acc0[0] += *p0; acc1[0] += *p1; }
  }
  if (k < s1) {
    const float* p0 = src + (size_t)col[k] * F + lane * VPT;
    if constexpr (VPT == 2) { float2 a = *(const float2*)p0; acc0[0] += a.x; acc0[1] += a.y; }
    else acc0[0] += *p0;
  }
  const float sc = (s1 > s0) ? 1.0f / (float)(s1 - s0) : 0.f;
  float* d = dst + (size_t)row * F + lane * VPT;
  #pragma unroll
  for (int i = 0; i < VPT; i++) {
    float v = (acc0[i] + acc1[i]) * sc + bias[lane * VPT + i];
    if (RELU) v = fmaxf(v, 0.f);
    d[i] = v;
  }
}

extern "C" void kernel_launch(void* const* d_in, const int* in_sizes, int n_in,
                              void* d_out, int out_size, void* d_ws, size_t ws_size,
                              hipStream_t stream) {
  const float* x  = (const float*)d_in[0];
  const int*   hi = (const int*)d_in[1];
  const float* W1 = (const float*)d_in[2];
  const float* b1 = (const float*)d_in[3];
  const float* W2 = (const float*)d_in[4];
  const float* b2 = (const float*)d_in[5];
  float* out = (float*)d_out;
  const int* nidx = hi;             // row 0: node indices
  const int* eidx = hi + NNZV;      // row 1: edge indices

  char* w = (char*)d_ws;
  int* off_e = (int*)w;                          // 100001 ints
  int* off_v = (int*)(w + 524288);               // 100001 ints
  int* cur_e = (int*)(w + 1048576);              // 100000 ints (counts -> cursors)
  int* cur_v = (int*)(w + 1572864);              // 100000 ints
  int* col_e = (int*)(w + 2097152);              // 1.6M ints
  int* col_v = (int*)(w + 8650752);              // 1.6M ints
  float* bufA = (float*)(w + 15728640);          // 51.2 MB node buf (F=128)
  float* bufB = (float*)(w + 15728640 + 51200000); // 51.2 MB edge buf
  float* g2  = bufB;                             // layer2: N x 64 (25.6 MB)
  float* me2 = bufB + (size_t)NODES * 64;        // layer2 edge buf: E x 64 (25.6 MB)

  // ---- CSR build (both directions) ----
  hipMemsetAsync(w + 1048576, 0, 1048576, stream);  // zero cur_e + cur_v
  hist_kernel<<<(NNZV + 255) / 256, 256, 0, stream>>>(nidx, eidx, cur_v, cur_e, NNZV);
  scan_kernel<<<2, 1024, 0, stream>>>(cur_e, off_e, cur_v, off_v, EDGES);
  fill_kernel<<<(NNZV + 255) / 256, 256, 0, stream>>>(nidx, eidx, cur_v, cur_e, col_v, col_e, NNZV);

  // ---- conv1 (F=128) ----
  gemm_kernel<128><<<512, 256, 0, stream>>>(x, W1, bufA, NODES);                    // h1 = x@W1
  gather_n2e<128><<<(EDGES + 3) / 4, 256, 0, stream>>>(off_e, col_e, bufA, bufB, EDGES);
  gather_e2n<128, true><<<(NODES + 3) / 4, 256, 0, stream>>>(off_v, col_v, bufB, b1, bufA, NODES);

  // ---- conv2 (F=64) ----
  gemm_kernel<64><<<768, 256, 0, stream>>>(bufA, W2, g2, NODES);                    // g2 = h@W2
  gather_n2e<64><<<(EDGES + 3) / 4, 256, 0, stream>>>(off_e, col_e, g2, me2, EDGES);
  gather_e2n<64, false><<<(NODES + 3) / 4, 256, 0, stream>>>(off_v, col_v, me2, b2, out, NODES);
}

// Round 3
// 810.756 us; speedup vs baseline: 10.3226x; 1.2681x over previous
//
#include <hip/hip_runtime.h>

#define NODES 100000
#define EDGES 100000
#define NNZV  1600000
#define FB    128           // blocks per range-group (hist/fill)
#define NCH   98            // scan chunks per array: ceil(100000/1024)

// ================= CSR build: range-partitioned (XCD-local) =================
// 16 groups: g in [0,8) filters on edge index, g in [8,16) on node index.
// group g runs on XCD (g&7) via blockIdx%8 round-robin [perf heuristic only].
__global__ __launch_bounds__(256) void hist_kernel(const int* __restrict__ nidx,
                                                   const int* __restrict__ eidx,
                                                   int* __restrict__ cnt_v, int* __restrict__ cnt_e) {
  const int grp = blockIdx.x & 15;
  const int blk = blockIdx.x >> 4;
  const bool is_e = grp < 8;
  const int lo = (grp & 7) * (EDGES / 8), hi = lo + (EDGES / 8);
  const int chunk = (NNZV + FB - 1) / FB;
  const int j1 = min(blk * chunk + chunk, NNZV);
  const int* __restrict__ key = is_e ? eidx : nidx;
  int* __restrict__ cnt = is_e ? cnt_e : cnt_v;
  for (int j = blk * chunk + threadIdx.x; j < j1; j += 256) {
    int k = key[j];
    if (k >= lo && k < hi) atomicAdd(&cnt[k], 1);
  }
}

__global__ __launch_bounds__(256) void fill_kernel(const int* __restrict__ nidx,
                                                   const int* __restrict__ eidx,
                                                   int* __restrict__ cur_v, int* __restrict__ cur_e,
                                                   int* __restrict__ col_v, int* __restrict__ col_e) {
  const int grp = blockIdx.x & 15;
  const int blk = blockIdx.x >> 4;
  const bool is_e = grp < 8;
  const int lo = (grp & 7) * (EDGES / 8), hi = lo + (EDGES / 8);
  const int chunk = (NNZV + FB - 1) / FB;
  const int j1 = min(blk * chunk + chunk, NNZV);
  const int* __restrict__ key = is_e ? eidx : nidx;
  const int* __restrict__ val = is_e ? nidx : eidx;
  int* __restrict__ cur = is_e ? cur_e : cur_v;
  int* __restrict__ col = is_e ? col_e : col_v;
  for (int j = blk * chunk + threadIdx.x; j < j1; j += 256) {
    int k = key[j];
    if (k >= lo && k < hi) {
      int p = atomicAdd(&cur[k], 1);
      col[p] = val[j];
    }
  }
}

// ================= 3-phase exclusive scan over cur_e / cur_v =================
__global__ __launch_bounds__(256) void scan_phase1(const int* __restrict__ cur_e,
                                                   const int* __restrict__ cur_v,
                                                   int* __restrict__ part) {
  const int b = blockIdx.x;                       // 0..2*NCH-1
  const bool is_v = b >= NCH;
  const int* src = is_v ? cur_v : cur_e;
  const int base = (is_v ? b - NCH : b) * 1024;
  const int tid = threadIdx.x, lane = tid & 63, wid = tid >> 6;
  int s = 0;
  #pragma unroll
  for (int i = 0; i < 4; i++) {
    int idx = base + tid * 4 + i;
    if (idx < EDGES) s += src[idx];
  }
  #pragma unroll
  for (int d = 1; d < 64; d <<= 1) s += __shfl_xor(s, d);
  __shared__ int ws[4];
  if (lane == 0) ws[wid] = s;
  __syncthreads();
  if (tid == 0) part[b] = ws[0] + ws[1] + ws[2] + ws[3];
}

__global__ void scan_phase2(int* __restrict__ part, int* __restrict__ off_e, int* __restrict__ off_v) {
  if (threadIdx.x == 0) {
    int a = 0;
    for (int i = 0; i < NCH; i++) { int t = part[i]; part[i] = a; a += t; }
    off_e[EDGES] = a;
    int c = 0;
    for (int i = NCH; i < 2 * NCH; i++) { int t = part[i]; part[i] = c; c += t; }
    off_v[NODES] = c;
  }
}

__global__ __launch_bounds__(256) void scan_phase3(const int* __restrict__ part,
                                                   int* __restrict__ cur_e, int* __restrict__ off_e,
                                                   int* __restrict__ cur_v, int* __restrict__ off_v) {
  const int b = blockIdx.x;
  const bool is_v = b >= NCH;
  int* __restrict__ cnt = is_v ? cur_v : cur_e;   // counts -> cursors
  int* __restrict__ off = is_v ? off_v : off_e;
  const int base = (is_v ? b - NCH : b) * 1024;
  const int tid = threadIdx.x, lane = tid & 63, wid = tid >> 6;
  int vals[4]; int s = 0;
  #pragma unroll
  for (int i = 0; i < 4; i++) {
    int idx = base + tid * 4 + i;
    vals[i] = (idx < EDGES) ? cnt[idx] : 0;
    s += vals[i];
  }
  int x = s;
  #pragma unroll
  for (int d = 1; d < 64; d <<= 1) { int t = __shfl_up(x, d); if (lane >= d) x += t; }
  __shared__ int ws[4];
  if (lane == 63) ws[wid] = x;
  __syncthreads();
  int wbase = 0;
  for (int k = 0; k < wid; k++) wbase += ws[k];
  int excl = part[b] + wbase + x - s;
  #pragma unroll
  for (int i = 0; i < 4; i++) {
    int idx = base + tid * 4 + i;
    if (idx < EDGES) { off[idx] = excl; cnt[idx] = excl; }
    excl += vals[i];
  }
}

// ================= GEMM: Y[M,N] = X[M,128] @ W[128,N] =================
template<int N>
__global__ __launch_bounds__(256) void gemm_kernel(const float* __restrict__ X,
                                                   const float* __restrict__ W,
                                                   float* __restrict__ Y, int M) {
  __shared__ float sW[128 * N];
  __shared__ float sX[4][8 * 128];
  const int tid = threadIdx.x, wave = tid >> 6, lane = tid & 63;
  for (int i = tid * 4; i < 128 * N; i += 1024)
    *(float4*)(sW + i) = *(const float4*)(W + i);
  __syncthreads();
  constexpr int CPL = N / 64;
  for (int chunk = blockIdx.x * 32; chunk < M; chunk += gridDim.x * 32) {
    const int row0 = chunk + wave * 8;
    {
      const float4* src = (const float4*)(X + (size_t)row0 * 128);
      float4* dst = (float4*)sX[wave];
      #pragma unroll
      for (int i = 0; i < 4; i++) dst[lane + 64 * i] = src[lane + 64 * i];
    }
    float acc[8][CPL];
    #pragma unroll
    for (int r = 0; r < 8; r++)
      #pragma unroll
      for (int c = 0; c < CPL; c++) acc[r][c] = 0.f;
    const float* xw = sX[wave];
    #pragma unroll 2
    for (int k = 0; k < 128; k += 4) {
      float4 xr[8];
      #pragma unroll
      for (int r = 0; r < 8; r++) xr[r] = *(const float4*)(xw + r * 128 + k);
      #pragma unroll
      for (int kk = 0; kk < 4; kk++) {
        #pragma unroll
        for (int c = 0; c < CPL; c++) {
          float w = sW[(k + kk) * N + lane + 64 * c];
          #pragma unroll
          for (int r = 0; r < 8; r++)
            acc[r][c] = fmaf(((const float*)&xr[r])[kk], w, acc[r][c]);
        }
      }
    }
    #pragma unroll
    for (int r = 0; r < 8; r++)
      #pragma unroll
      for (int c = 0; c < CPL; c++)
        Y[(size_t)(row0 + r) * N + lane + 64 * c] = acc[r][c];
  }
}

// ========== gather node->edge: dst[e] = (1/deg_e) * sum_{v in e} src[v] ==========
template<int F>
__global__ __launch_bounds__(256) void gather_n2e(const int* __restrict__ off, const int* __restrict__ col,
                                                  const float* __restrict__ src, float* __restrict__ dst,
                                                  int nrows) {
  constexpr int VPT = F / 64;
  const int row = blockIdx.x * 4 + (threadIdx.x >> 6);
  if (row >= nrows) return;
  const int lane = threadIdx.x & 63;
  const int s0 = off[row], s1 = off[row + 1];
  float acc0[VPT] = {}, acc1[VPT] = {};
  int k = s0;
  for (; k + 1 < s1; k += 2) {
    int c0 = col[k], c1 = col[k + 1];
    const float* p0 = src + (size_t)c0 * F + lane * VPT;
    const float* p1 = src + (size_t)c1 * F + lane * VPT;
    if constexpr (VPT == 2) {
      float2 a = *(const float2*)p0, b = *(const float2*)p1;
      acc0[0] += a.x; acc0[1] += a.y; acc1[0] += b.x; acc1[1] += b.y;
    } else { acc0[0] += *p0; acc1[0] += *p1; }
  }
  if (k < s1) {
    const float* p0 = src + (size_t)col[k] * F + lane * VPT;
    if constexpr (VPT == 2) { float2 a = *(const float2*)p0; acc0[0] += a.x; acc0[1] += a.y; }
    else acc0[0] += *p0;
  }
  const float sc = (s1 > s0) ? 1.0f / (float)(s1 - s0) : 0.f;
  float* d = dst + (size_t)row * F + lane * VPT;
  if constexpr (VPT == 2) { *(float2*)d = make_float2((acc0[0] + acc1[0]) * sc, (acc0[1] + acc1[1]) * sc); }
  else d[0] = (acc0[0] + acc1[0]) * sc;
}

// ====== gather edge->node + bias (+relu): out[v] = relu((1/deg_v)*sum src[e] + b) ======
template<int F, bool RELU>
__global__ __launch_bounds__(256) void gather_e2n(const int* __restrict__ off, const int* __restrict__ col,
                                                  const float* __restrict__ src, const float* __restrict__ bias,
                                                  float* __restrict__ dst, int nrows) {
  constexpr int VPT = F / 64;
  const int row = blockIdx.x * 4 + (threadIdx.x >> 6);
  if (row >= nrows) return;
  const int lane = threadIdx.x & 63;
  const int s0 = off[row], s1 = off[row + 1];
  float acc0[VPT] = {}, acc1[VPT] = {};
  int k = s0;
  for (; k + 1 < s1; k += 2) {
    int c0 = col[k], c1 = col[k + 1];
    const float* p0 = src + (size_t)c0 * F + lane * VPT;
    const float* p1 = src + (size_t)c1 * F + lane * VPT;
    if constexpr (VPT == 2) {
      float2 a = *(const float2*)p0, b = *(const float2*)p1;
      acc0[0] += a.x; acc0[1] += a.y; acc1[0] += b.x; acc1[1] += b.y;
    } else { acc0[0] += *p0; acc1[0] += *p1; }
  }
  if (k < s1) {
    const float* p0 = src + (size_t)col[k] * F + lane * VPT;
    if constexpr (VPT == 2) { float2 a = *(const float2*)p0; acc0[0] += a.x; acc0[1] += a.y; }
    else acc0[0] += *p0;
  }
  const float sc = (s1 > s0) ? 1.0f / (float)(s1 - s0) : 0.f;
  float* d = dst + (size_t)row * F + lane * VPT;
  #pragma unroll
  for (int i = 0; i < VPT; i++) {
    float v = (acc0[i] + acc1[i]) * sc + bias[lane * VPT + i];
    if (RELU) v = fmaxf(v, 0.f);
    d[i] = v;
  }
}

extern "C" void kernel_launch(void* const* d_in, const int* in_sizes, int n_in,
                              void* d_out, int out_size, void* d_ws, size_t ws_size,
                              hipStream_t stream) {
  const float* x  = (const float*)d_in[0];
  const int*   hi = (const int*)d_in[1];
  const float* W1 = (const float*)d_in[2];
  const float* b1 = (const float*)d_in[3];
  const float* W2 = (const float*)d_in[4];
  const float* b2 = (const float*)d_in[5];
  float* out = (float*)d_out;
  const int* nidx = hi;             // row 0: node indices
  const int* eidx = hi + NNZV;      // row 1: edge indices

  char* w = (char*)d_ws;
  int* off_e = (int*)w;                            // 100001 ints
  int* off_v = (int*)(w + 524288);                 // 100001 ints
  int* cur_e = (int*)(w + 1048576);                // 100000 ints (counts -> cursors)
  int* cur_v = (int*)(w + 1572864);                // 100000 ints
  int* part  = (int*)(w + 2000000);                // 196 ints
  int* col_e = (int*)(w + 2097152);                // 1.6M ints
  int* col_v = (int*)(w + 8650752);                // 1.6M ints
  float* bufA = (float*)(w + 15728640);            // 51.2 MB node buf (F=128)
  float* bufB = (float*)(w + 15728640 + 51200000); // 51.2 MB edge buf
  float* g2  = bufB;                               // layer2: N x 64
  float* me2 = bufB + (size_t)NODES * 64;          // layer2 edge buf: E x 64

  // ---- CSR build (both directions), XCD-range-partitioned ----
  hipMemsetAsync(w + 1048576, 0, 1048576, stream);     // zero cur_e + cur_v
  hist_kernel<<<16 * FB, 256, 0, stream>>>(nidx, eidx, cur_v, cur_e);
  scan_phase1<<<2 * NCH, 256, 0, stream>>>(cur_e, cur_v, part);
  scan_phase2<<<1, 64, 0, stream>>>(part, off_e, off_v);
  scan_phase3<<<2 * NCH, 256, 0, stream>>>(part, cur_e, off_e, cur_v, off_v);
  fill_kernel<<<16 * FB, 256, 0, stream>>>(nidx, eidx, cur_v, cur_e, col_v, col_e);

  // ---- conv1 (F=128) ----
  gemm_kernel<128><<<512, 256, 0, stream>>>(x, W1, bufA, NODES);
  gather_n2e<128><<<(EDGES + 3) / 4, 256, 0, stream>>>(off_e, col_e, bufA, bufB, EDGES);
  gather_e2n<128, true><<<(NODES + 3) / 4, 256, 0, stream>>>(off_v, col_v, bufB, b1, bufA, NODES);

  // ---- conv2 (F=64) ----
  gemm_kernel<64><<<768, 256, 0, stream>>>(bufA, W2, g2, NODES);
  gather_n2e<64><<<(EDGES + 3) / 4, 256, 0, stream>>>(off_e, col_e, g2, me2, EDGES);
  gather_e2n<64, false><<<(NODES + 3) / 4, 256, 0, stream>>>(off_v, col_v, me2, b2, out, NODES);
}